// Round 8
// baseline (2463.680 us; speedup 1.0000x reference)
//
#include <hip/hip_runtime.h>
#include <hip/hip_bf16.h>

#define NN 3136
#define CC 512
#define BBATCH 8

typedef __attribute__((ext_vector_type(8))) short short8;
typedef __attribute__((ext_vector_type(4))) float f32x4;

static __device__ __forceinline__ unsigned int pkbf(float a, float b) {
    union { __hip_bfloat162 h; unsigned int u; } v;
    v.h = __float22bfloat162_rn(make_float2(a, b));
    return v.u;
}
static __device__ __forceinline__ unsigned short sbf(float a) {
    union { __hip_bfloat16 h; unsigned short u; } v;
    v.h = __float2bfloat16(a);
    return v.u;
}

// ---------------- norms: inv[t][b][n] = 1/max(||f_t[b,:,n]||, 1e-12) ----------------
__global__ void norms_k(const float* __restrict__ f1, const float* __restrict__ f2,
                        const float* __restrict__ f3, float* __restrict__ inv) {
    int g = blockIdx.x * 256 + threadIdx.x;          // < 3*8*3136 = 75264
    int t = g / (BBATCH * NN);
    int r = g - t * (BBATCH * NN);
    int b = r / NN;
    int n = r - b * NN;
    const float* f = (t == 0) ? f1 : (t == 1) ? f2 : f3;
    const float* p = f + (size_t)b * CC * NN + n;
    float ss = 0.f;
#pragma unroll 8
    for (int c = 0; c < CC; ++c) { float x = p[(size_t)c * NN]; ss = fmaf(x, x, ss); }
    inv[g] = 1.0f / fmaxf(sqrtf(ss), 1e-12f);
}

// ---------------- init: out = fm1 ----------------
__global__ void init_k(const float4* __restrict__ src, float4* __restrict__ dst) {
    int g = blockIdx.x * 256 + threadIdx.x;
    dst[g] = src[g];
}

// ---------------- fused attention branch, out += 0.001 * (fk @ softmax(-q^k^)^T) ----------------
// Single-buffered KT/V (79KB LDS) -> 2 WGs/CU; cross-WG overlap hides staging
// and barrier stalls. 2 barriers/iter:
//   score(KT) | P-write | bar1 | PV(V,P) + KT-write(it+1) | bar2 | V-write(it+1)
// KT reads finish before bar1 -> safe to overwrite KT after bar1.
// V reads finish before bar2 -> safe to overwrite V after bar2.
// Scores bounded in [-1,1] -> p = exp(s), no running max.
static constexpr int VBASE = 16384;   // V at smem+16384 (512 x 40 ush)
static constexpr int PBASE = 36864;   // P at smem+36864 (64 x 40 ush)
static constexpr int VSTR  = 40;
static constexpr int SMEMN = 39424;   // total ushorts (78848 B)

__launch_bounds__(512, 4)
__global__ void attn_fused_k(const float* __restrict__ fq_all,
                             const float* __restrict__ f2_all,
                             const float* __restrict__ f3_all,
                             const float* __restrict__ invws,
                             float* __restrict__ out) {
    __shared__ __align__(16) unsigned short smem[SMEMN];
    __shared__ float denbuf[8][16];

    unsigned short* pp = smem + PBASE;               // [64][VSTR]
    unsigned short* qstage = smem;                   // aliases KT+V (pre-loop only)

    const int tid = threadIdx.x;
    const int w = tid >> 6, l = tid & 63;
    const int u = blockIdx.x;
    const int batch = u & 7;                          // 8 batches -> 8 XCDs
    const int unit = u >> 3;                          // 0..97
    const int br = unit & 1;
    const int qt = unit >> 1;                         // 0..48
    const int n0 = qt * 64;

    const float* fq = fq_all + (size_t)batch * CC * NN;
    const float* fk = (br ? f3_all : f2_all) + (size_t)batch * CC * NN;
    const float* inv1 = invws + batch * NN;
    const float* invk = invws + (1 + br) * (BBATCH * NN) + batch * NN;

    // ---- Q stage: [n][c] bf16, value = -f1*inv1 (sign folded), XOR-swizzled rows
    {
        int n = tid & 63, grp = tid >> 6;             // grp 0..7
        float s = -inv1[n0 + n];
        const float* src = fq + n0 + n;
        int sw = (n & 7) << 3;
#pragma unroll 4
        for (int ssi = 0; ssi < 16; ++ssi) {
            int cb = grp * 4 + 32 * ssi;
            int b0 = cb * NN;
            float x0 = src[b0], x1 = src[b0 + NN];
            float x2 = src[b0 + 2 * NN], x3 = src[b0 + 3 * NN];
            uint2 y = { pkbf(x0 * s, x1 * s), pkbf(x2 * s, x3 * s) };
            *(uint2*)&qstage[n * 512 + (cb ^ sw)] = y;
        }
    }
    __syncthreads();

    // ---- Q fragments to registers: wave w owns n-cols 16*(w&3)..+15, all 16 k-steps
    short8 qf[16];
    {
        int nQ = 16 * (w & 3) + (l & 15);
        int sw = (nQ & 7) << 3;
#pragma unroll
        for (int ks = 0; ks < 16; ++ks)
            qf[ks] = *(const short8*)&qstage[nQ * 512 + ((ks * 32 + ((l >> 4) << 3)) ^ sw)];
    }
    __syncthreads();

    const int mstg = tid & 31, gstg = tid >> 5;       // staging decomposition
    const int swm = (mstg & 7) << 3;

    // issue the 32 global loads for tile `it` into xb
    auto stage_load = [&](int it, float* xb) {
        const float* src = fk + it * 32 + mstg;
#pragma unroll
        for (int ssi = 0; ssi < 8; ++ssi) {
            int b0 = (gstg * 4 + 64 * ssi) * NN;
            xb[ssi * 4 + 0] = src[b0];
            xb[ssi * 4 + 1] = src[b0 + NN];
            xb[ssi * 4 + 2] = src[b0 + 2 * NN];
            xb[ssi * 4 + 3] = src[b0 + 3 * NN];
        }
    };
    auto stage_write_kt = [&](int it, const float* xb) {
        float sk = invk[it * 32 + mstg];
        unsigned short* KT = smem;
#pragma unroll
        for (int ssi = 0; ssi < 8; ++ssi) {
            int cb = gstg * 4 + 64 * ssi;
            uint2 y = { pkbf(xb[ssi*4+0] * sk, xb[ssi*4+1] * sk),
                        pkbf(xb[ssi*4+2] * sk, xb[ssi*4+3] * sk) };
            *(uint2*)&KT[mstg * 512 + (cb ^ swm)] = y;
        }
    };
    auto stage_write_v = [&](const float* xb) {
        unsigned short* V = smem + VBASE;
#pragma unroll
        for (int ssi = 0; ssi < 8; ++ssi) {
            int cb = gstg * 4 + 64 * ssi;
            unsigned short* vb = &V[cb * VSTR + mstg];
            vb[0]        = sbf(xb[ssi*4+0]);
            vb[VSTR]     = sbf(xb[ssi*4+1]);
            vb[2 * VSTR] = sbf(xb[ssi*4+2]);
            vb[3 * VSTR] = sbf(xb[ssi*4+3]);
        }
    };

    f32x4 acc[8][2];
#pragma unroll
    for (int ci = 0; ci < 8; ++ci) {
        acc[ci][0] = (f32x4){0.f, 0.f, 0.f, 0.f};
        acc[ci][1] = (f32x4){0.f, 0.f, 0.f, 0.f};
    }
    float den_part = 0.f;
    float xb[32];

    stage_load(0, xb);
    stage_write_kt(0, xb);
    stage_write_v(xb);
    __syncthreads();

    const int mt = w >> 2, nt = w & 3;                // score-phase wave layout
    const int np = w & 1, cg = w >> 1;                // PV-phase wave layout
    const int g = l >> 4, li = l & 15;
    const int mA = 16 * mt + li;                      // score A-row (m)
    const int swA = (mA & 7) << 3;
    const int nP = 16 * nt + li;                      // n index for P / den

    for (int it = 0; it < 98; ++it) {
        if (it < 97) stage_load(it + 1, xb);          // global -> regs

        // scores: D[m][n] = sum_c KT[m,c] * Qneg[c,n]
        f32x4 sacc = (f32x4){0.f, 0.f, 0.f, 0.f};
        const unsigned short* KT = smem;
        __builtin_amdgcn_s_setprio(1);
#pragma unroll
        for (int ks = 0; ks < 16; ++ks) {
            short8 af = *(const short8*)&KT[mA * 512 + ((ks * 32 + (g << 3)) ^ swA)];
            sacc = __builtin_amdgcn_mfma_f32_16x16x32_bf16(af, qf[ks], sacc, 0, 0, 0);
        }
        __builtin_amdgcn_s_setprio(0);
        float p0 = __expf(sacc[0]), p1 = __expf(sacc[1]);
        float p2 = __expf(sacc[2]), p3 = __expf(sacc[3]);
        den_part += (p0 + p1) + (p2 + p3);
        uint2 pw = { pkbf(p0, p1), pkbf(p2, p3) };
        *(uint2*)&pp[nP * VSTR + 16 * mt + 4 * g] = pw;   // P[n][m]

        __syncthreads();                              // bar1: P visible; KT reads done

        // PV: O^T[c][n] += sum_m V[c,m] * P^T[m,n]; wave owns 8 c-tiles x n-pair
        const unsigned short* V = smem + VBASE;
        short8 bf0 = *(const short8*)&pp[(32 * np + li) * VSTR + (g << 3)];
        short8 bf1 = *(const short8*)&pp[(32 * np + 16 + li) * VSTR + (g << 3)];
        const unsigned short* vbase = &V[(128 * cg + li) * VSTR + (g << 3)];
        __builtin_amdgcn_s_setprio(1);
#pragma unroll
        for (int ci = 0; ci < 8; ++ci) {
            short8 af = *(const short8*)&vbase[ci * 16 * VSTR];
            acc[ci][0] = __builtin_amdgcn_mfma_f32_16x16x32_bf16(af, bf0, acc[ci][0], 0, 0, 0);
            acc[ci][1] = __builtin_amdgcn_mfma_f32_16x16x32_bf16(af, bf1, acc[ci][1], 0, 0, 0);
        }
        __builtin_amdgcn_s_setprio(0);

        if (it < 97) stage_write_kt(it + 1, xb);      // KT free after bar1 (score done)

        __syncthreads();                              // bar2: V/P reads done; KT writes visible

        if (it < 97) stage_write_v(xb);               // V free after bar2; visible by next bar1
    }

    // ---- den reduction (score-wave layout), then epilogue in PV layout
    den_part += __shfl_xor(den_part, 16);
    den_part += __shfl_xor(den_part, 32);
    if (l < 16) denbuf[w][l] = den_part;
    __syncthreads();
    float sc0 = 0.001f / (denbuf[2 * np + 0][li] + denbuf[4 + 2 * np + 0][li]);
    float sc1 = 0.001f / (denbuf[2 * np + 1][li] + denbuf[4 + 2 * np + 1][li]);

    float* op = out + (size_t)batch * CC * NN + n0;
    const int ncol0 = 16 * (2 * np + 0) + li;
    const int ncol1 = 16 * (2 * np + 1) + li;
#pragma unroll
    for (int ci = 0; ci < 8; ++ci) {
        int cbase = 16 * (8 * cg + ci) + 4 * g;
#pragma unroll
        for (int r = 0; r < 4; ++r) {
            atomicAdd(&op[(size_t)(cbase + r) * NN + ncol0], acc[ci][0][r] * sc0);
            atomicAdd(&op[(size_t)(cbase + r) * NN + ncol1], acc[ci][1][r] * sc1);
        }
    }
}

extern "C" void kernel_launch(void* const* d_in, const int* in_sizes, int n_in,
                              void* d_out, int out_size, void* d_ws, size_t ws_size,
                              hipStream_t stream) {
    (void)in_sizes; (void)n_in; (void)out_size; (void)ws_size;
    const float* f1 = (const float*)d_in[0];
    const float* f2 = (const float*)d_in[1];
    const float* f3 = (const float*)d_in[2];
    float* out = (float*)d_out;
    float* inv = (float*)d_ws;                        // 3*8*3136 floats = 301 KB

    norms_k<<<294, 256, 0, stream>>>(f1, f2, f3, inv);
    init_k<<<12544, 256, 0, stream>>>((const float4*)f1, (float4*)out);
    attn_fused_k<<<784, 512, 0, stream>>>(f1, f2, f3, inv, out);
}

// Round 9
// 851.112 us; speedup vs baseline: 2.8947x; 2.8947x over previous
//
#include <hip/hip_runtime.h>
#include <hip/hip_bf16.h>

#define NN 3136
#define CC 512
#define BBATCH 8

typedef unsigned short ush;
typedef __attribute__((ext_vector_type(8))) short short8;
typedef __attribute__((ext_vector_type(4))) float f32x4;

static __device__ __forceinline__ unsigned int pkbf(float a, float b) {
    union { __hip_bfloat162 h; unsigned int u; } v;
    v.h = __float22bfloat162_rn(make_float2(a, b));
    return v.u;
}
static __device__ __forceinline__ ush sbf(float a) {
    union { __hip_bfloat16 h; ush u; } v;
    v.h = __float2bfloat16(a);
    return v.u;
}
static __device__ __forceinline__ void gl_lds16(const void* g, void* l) {
    __builtin_amdgcn_global_load_lds((const __attribute__((address_space(1))) void*)g,
                                     (__attribute__((address_space(3))) void*)l, 16, 0, 0);
}

// ---- ws layout (bytes) ----
static constexpr size_t INV_OFS  = 0;                       // 3*8*3136 f32 = 301056
static constexpr size_t DEN_OFS  = 301056;                  // 2*8*3136 f32 = 200704
static constexpr size_t PREP_OFS = 501760;                  // 5 bf16 tensors
static constexpr size_t TEN_ELE  = (size_t)BBATCH * NN * CC;        // 12,845,056 elems
static constexpr size_t P_OFS    = PREP_OFS + 5 * TEN_ELE * 2;      // 128,952,320
static constexpr size_t PER_TILE = 2ull * BBATCH * 128 * NN * 2;    // bytes per n-tile, both br

// ---------------- norms: inv[t][b][n] = 1/max(||f_t[b,:,n]||,1e-12) ----------------
__global__ void norms_k(const float* __restrict__ f1, const float* __restrict__ f2,
                        const float* __restrict__ f3, float* __restrict__ inv) {
    int gg = blockIdx.x * 256 + threadIdx.x;
    int t = gg / (BBATCH * NN);
    int r = gg - t * (BBATCH * NN);
    int b = r / NN;
    int n = r - b * NN;
    const float* f = (t == 0) ? f1 : (t == 1) ? f2 : f3;
    const float* p = f + (size_t)b * CC * NN + n;
    float ss = 0.f;
#pragma unroll 8
    for (int c = 0; c < CC; ++c) { float x = p[(size_t)c * NN]; ss = fmaf(x, x, ss); }
    inv[gg] = 1.0f / fmaxf(sqrtf(ss), 1e-12f);
}

// ---------------- prepT: normalized transposed bf16  dst[t][b][n][c] ----------------
__global__ void prepT_k(const float* __restrict__ f1, const float* __restrict__ f2,
                        const float* __restrict__ f3, const float* __restrict__ inv,
                        ush* __restrict__ prep) {
    __shared__ float lt[64][65];
    const int tid = threadIdx.x;
    const int xt = blockIdx.x, yc = blockIdx.y, z = blockIdx.z;
    const int t = z >> 3, b = z & 7;
    const float* f = (t == 0) ? f1 : (t == 1) ? f2 : f3;
    const int n0 = xt * 64, c0 = yc * 64;
    const float* src = f + (size_t)b * CC * NN + (size_t)c0 * NN + n0;
    const int col4 = tid & 15, rw = tid >> 4;
#pragma unroll
    for (int p = 0; p < 4; ++p) {
        int row = p * 16 + rw;
        float4 v = *(const float4*)&src[(size_t)row * NN + col4 * 4];
        lt[row][col4 * 4 + 0] = v.x; lt[row][col4 * 4 + 1] = v.y;
        lt[row][col4 * 4 + 2] = v.z; lt[row][col4 * 4 + 3] = v.w;
    }
    __syncthreads();
    const float* ivp = inv + (size_t)t * BBATCH * NN + (size_t)b * NN + n0;
    ush* dst = prep + (size_t)t * TEN_ELE + ((size_t)b * NN + n0) * CC + c0;
    const int cchunk = tid & 7, nr = tid >> 3;
#pragma unroll
    for (int p = 0; p < 2; ++p) {
        int n = p * 32 + nr;
        float s = ivp[n]; if (t == 0) s = -s;       // fold the minus into q-hat
        unsigned u0 = pkbf(lt[cchunk * 8 + 0][n] * s, lt[cchunk * 8 + 1][n] * s);
        unsigned u1 = pkbf(lt[cchunk * 8 + 2][n] * s, lt[cchunk * 8 + 3][n] * s);
        unsigned u2 = pkbf(lt[cchunk * 8 + 4][n] * s, lt[cchunk * 8 + 5][n] * s);
        unsigned u3 = pkbf(lt[cchunk * 8 + 6][n] * s, lt[cchunk * 8 + 7][n] * s);
        uint4 y = { u0, u1, u2, u3 };
        *(uint4*)&dst[(size_t)n * CC + cchunk * 8] = y;
    }
}

// ---------------- prepC: raw f2/f3 -> bf16 [b][c][m] ----------------
__global__ void prepC_k(const float* __restrict__ f2, const float* __restrict__ f3,
                        ush* __restrict__ vbf) {
    const size_t idx = ((size_t)blockIdx.x * 256 + threadIdx.x) * 8;
    const float* s = blockIdx.y ? f3 : f2;
    ush* d = vbf + (size_t)blockIdx.y * TEN_ELE + idx;
    float4 a = *(const float4*)&s[idx];
    float4 b2 = *(const float4*)&s[idx + 4];
    uint4 y = { pkbf(a.x, a.y), pkbf(a.z, a.w), pkbf(b2.x, b2.y), pkbf(b2.z, b2.w) };
    *(uint4*)d = y;
}

// ---------------- gemmA: P[n][m] = exp(qhatT[n,:].khatT[m,:]); den[n] += rowsum ----------------
__global__ __launch_bounds__(256) void gemmA_k(const ush* __restrict__ qhatT,
        const ush* __restrict__ khatT, ush* __restrict__ P, size_t PBRel,
        float* __restrict__ den, int cbt, int rowcap) {
    __shared__ __align__(16) ush smem[17408];     // staging 16384 | PT 128x136
    const int tid = threadIdx.x, w = tid >> 6, l = tid & 63;
    const int mt = blockIdx.x % 25, ntl = blockIdx.x / 25;
    const int b = blockIdx.y, br = blockIdx.z;
    const int n0 = (cbt + ntl) * 128, m0 = mt * 128;
    const ush* qT = qhatT + (size_t)b * NN * CC;
    const ush* kT = khatT + (size_t)br * TEN_ELE + (size_t)b * NN * CC;
    const int lrow = l >> 3, chunkL = (l & 7) ^ lrow;
    const int g = l >> 4, li = l & 15, nh = w & 1, mh = w >> 1;
    f32x4 acc[4][4];
#pragma unroll
    for (int i = 0; i < 4; ++i)
#pragma unroll
        for (int j = 0; j < 4; ++j) acc[i][j] = (f32x4){0.f, 0.f, 0.f, 0.f};

    for (int kk = 0; kk < 8; ++kk) {
        int c0 = kk * 64;
#pragma unroll
        for (int i = 0; i < 4; ++i) {
            int rb = i * 4 + w;
            int row = rb * 8 + lrow;
            int rA = n0 + row; rA = rA < NN ? rA : NN - 1;
            int rB = m0 + row; rB = rB < NN ? rB : NN - 1;
            gl_lds16(qT + (size_t)rA * CC + c0 + chunkL * 8, &smem[rb * 512]);
            gl_lds16(kT + (size_t)rB * CC + c0 + chunkL * 8, &smem[8192 + rb * 512]);
        }
        __syncthreads();
#pragma unroll
        for (int ks = 0; ks < 2; ++ks) {
            short8 af[4], bf[4];
#pragma unroll
            for (int i = 0; i < 4; ++i) {
                int rA = nh * 64 + i * 16 + li;
                af[i] = *(const short8*)&smem[rA * 64 + (((ks * 4 + g) ^ (rA & 7)) << 3)];
                int rB = mh * 64 + i * 16 + li;
                bf[i] = *(const short8*)&smem[8192 + rB * 64 + (((ks * 4 + g) ^ (rB & 7)) << 3)];
            }
#pragma unroll
            for (int i = 0; i < 4; ++i)
#pragma unroll
                for (int j = 0; j < 4; ++j)
                    acc[i][j] = __builtin_amdgcn_mfma_f32_16x16x32_bf16(af[i], bf[j], acc[i][j], 0, 0, 0);
        }
        __syncthreads();
    }
    // exp -> PT bounce (coalesced stores + den)
    ush* PT = smem;                                // [128][136]
#pragma unroll
    for (int i = 0; i < 4; ++i)
#pragma unroll
        for (int j = 0; j < 4; ++j) {
            int col = mh * 64 + j * 16 + li;
#pragma unroll
            for (int r = 0; r < 4; ++r) {
                int row = nh * 64 + i * 16 + 4 * g + r;
                PT[row * 136 + col] = sbf(__expf(acc[i][j][r]));
            }
        }
    __syncthreads();
    const int rowlim = (NN - n0) < 128 ? (NN - n0) : 128;
    const int mchunks = (NN - m0) < 128 ? ((NN - m0) >> 3) : 16;
    ush* Pg = P + (size_t)br * PBRel + (size_t)(b * rowcap + ntl * 128) * NN;
    float* denp = den + (size_t)(br * BBATCH + b) * NN;
    const int ck = tid & 15, rbase = tid >> 4;
#pragma unroll
    for (int pass = 0; pass < 8; ++pass) {
        int rr = rbase + pass * 16;
        uint4 v = *(const uint4*)&PT[rr * 136 + ck * 8];
        float s = 0.f;
        if (ck < mchunks) {
            unsigned vv[4] = { v.x, v.y, v.z, v.w };
#pragma unroll
            for (int q = 0; q < 4; ++q) {
                union { unsigned u; float f; } lo, hi;
                lo.u = vv[q] << 16; hi.u = vv[q] & 0xffff0000u;
                s += lo.f + hi.f;
            }
        }
        s += __shfl_xor(s, 1); s += __shfl_xor(s, 2);
        s += __shfl_xor(s, 4); s += __shfl_xor(s, 8);
        if (ck == 0 && rr < rowlim) atomicAdd(&denp[n0 + rr], s);
        if (rr < rowlim && ck < mchunks)
            *(uint4*)&Pg[(size_t)rr * NN + m0 + ck * 8] = v;
    }
}

// ---------------- gemmB: out = fm1 + 0.001*(V2.P2^T/den2 + V3.P3^T/den3) ----------------
__global__ __launch_bounds__(256) void gemmB_k(const ush* __restrict__ vbf,
        const ush* __restrict__ P, size_t PBRel, const float* __restrict__ den,
        const float* __restrict__ fm1, float* __restrict__ out, int cbt, int rowcap) {
    __shared__ __align__(16) ush smem[16384];
    const int tid = threadIdx.x, w = tid >> 6, l = tid & 63;
    const int ct = blockIdx.x & 3, ntl = blockIdx.x >> 2;
    const int b = blockIdx.y;
    const int c0 = ct * 128, n0 = (cbt + ntl) * 128;
    const int lrow = l >> 3, chunkL = (l & 7) ^ lrow;
    const int g = l >> 4, li = l & 15, ch = w & 1, nh = w >> 1;
    const float* d2p = den + (size_t)b * NN;
    const float* d3p = den + (size_t)(BBATCH + b) * NN;
    float d2[4], d3[4];
#pragma unroll
    for (int j = 0; j < 4; ++j) {
        int n = n0 + nh * 64 + j * 16 + li;
        int nc = n < NN ? n : NN - 1;
        d2[j] = d2p[nc]; d3[j] = d3p[nc];
    }
    f32x4 acc[4][4];
#pragma unroll
    for (int i = 0; i < 4; ++i)
#pragma unroll
        for (int j = 0; j < 4; ++j) acc[i][j] = (f32x4){0.f, 0.f, 0.f, 0.f};
    const int rowclamp = (NN - 1 - n0) < 127 ? (NN - 1 - n0) : 127;

    for (int gk = 0; gk < 98; ++gk) {
        int br = gk < 49 ? 1 : 0;                  // P3 first, then ratio-fold, then P2
        int km = gk < 49 ? gk : gk - 49;
        const ush* vA = vbf + (size_t)br * TEN_ELE + (size_t)b * CC * NN;
        const ush* pB = P + (size_t)br * PBRel + (size_t)(b * rowcap + ntl * 128) * NN;
        int mm0 = km * 64;
#pragma unroll
        for (int i = 0; i < 4; ++i) {
            int rb = i * 4 + w;
            int row = rb * 8 + lrow;
            int rloc = row < rowclamp ? row : rowclamp;
            gl_lds16(vA + (size_t)(c0 + row) * NN + mm0 + chunkL * 8, &smem[rb * 512]);
            gl_lds16(pB + (size_t)rloc * NN + mm0 + chunkL * 8, &smem[8192 + rb * 512]);
        }
        __syncthreads();
#pragma unroll
        for (int ks = 0; ks < 2; ++ks) {
            short8 af[4], bf[4];
#pragma unroll
            for (int i = 0; i < 4; ++i) {
                int rA = ch * 64 + i * 16 + li;
                af[i] = *(const short8*)&smem[rA * 64 + (((ks * 4 + g) ^ (rA & 7)) << 3)];
                int rB = nh * 64 + i * 16 + li;
                bf[i] = *(const short8*)&smem[8192 + rB * 64 + (((ks * 4 + g) ^ (rB & 7)) << 3)];
            }
#pragma unroll
            for (int i = 0; i < 4; ++i)
#pragma unroll
                for (int j = 0; j < 4; ++j)
                    acc[i][j] = __builtin_amdgcn_mfma_f32_16x16x32_bf16(af[i], bf[j], acc[i][j], 0, 0, 0);
        }
        __syncthreads();
        if (gk == 48) {
#pragma unroll
            for (int j = 0; j < 4; ++j) {
                float ratio = d2[j] / fmaxf(d3[j], 1e-30f);
#pragma unroll
                for (int i = 0; i < 4; ++i)
#pragma unroll
                    for (int r = 0; r < 4; ++r) acc[i][j][r] *= ratio;
            }
        }
    }
    const float* fb = fm1 + (size_t)b * CC * NN;
    float* ob = out + (size_t)b * CC * NN;
#pragma unroll
    for (int j = 0; j < 4; ++j) {
        int n = n0 + nh * 64 + j * 16 + li;
        if (n < NN) {
            float s2 = 0.001f / fmaxf(d2[j], 1e-30f);
#pragma unroll
            for (int i = 0; i < 4; ++i) {
                int cc = c0 + ch * 64 + i * 16 + 4 * g;
#pragma unroll
                for (int r = 0; r < 4; ++r) {
                    size_t o = (size_t)(cc + r) * NN + n;
                    ob[o] = fb[o] + s2 * acc[i][j][r];
                }
            }
        }
    }
}

// ================= fallback (proven R5 fused kernel, used only if ws too small) ===============
__global__ void init_k(const float4* __restrict__ src, float4* __restrict__ dst) {
    int gg = blockIdx.x * 256 + threadIdx.x;
    dst[gg] = src[gg];
}
static constexpr int FKTOFF = 16384, FVBASE = 32768, FVOFF = 20480, FPBASE = 73728, FVSTR = 40;
__launch_bounds__(512, 2)
__global__ void attn_fb_k(const float* __restrict__ fq_all, const float* __restrict__ f2_all,
                          const float* __restrict__ f3_all, const float* __restrict__ invws,
                          float* __restrict__ out) {
    __shared__ __align__(16) ush smem[2 * 16384 + 2 * 20480 + 64 * 40];
    __shared__ float denbuf[8][16];
    ush* pp = smem + FPBASE;
    ush* qstage = smem;
    const int tid = threadIdx.x, w = tid >> 6, l = tid & 63;
    const int u = blockIdx.x, batch = u & 7, unit = u >> 3, br = unit & 1, qt = unit >> 1;
    const int n0 = qt * 64;
    const float* fq = fq_all + (size_t)batch * CC * NN;
    const float* fk = (br ? f3_all : f2_all) + (size_t)batch * CC * NN;
    const float* inv1 = invws + batch * NN;
    const float* invk = invws + (1 + br) * (BBATCH * NN) + batch * NN;
    {
        int n = tid & 63, grp = tid >> 6;
        float s = -inv1[n0 + n];
        const float* src = fq + n0 + n;
        int sw = (n & 7) << 3;
#pragma unroll 4
        for (int ssi = 0; ssi < 16; ++ssi) {
            int cb = grp * 4 + 32 * ssi; int b0 = cb * NN;
            uint2 y = { pkbf(src[b0] * s, src[b0 + NN] * s),
                        pkbf(src[b0 + 2 * NN] * s, src[b0 + 3 * NN] * s) };
            *(uint2*)&qstage[n * 512 + (cb ^ sw)] = y;
        }
    }
    __syncthreads();
    short8 qf[16];
    {
        int nQ = 16 * (w & 3) + (l & 15);
        int sw = (nQ & 7) << 3;
#pragma unroll
        for (int ks = 0; ks < 16; ++ks)
            qf[ks] = *(const short8*)&qstage[nQ * 512 + ((ks * 32 + ((l >> 4) << 3)) ^ sw)];
    }
    __syncthreads();
    auto stage = [&](int it, int bb2) {
        int m = tid & 31, grp = tid >> 5;
        int m0 = it * 32;
        float sk = invk[m0 + m];
        const float* src = fk + m0 + m;
        ush* KT = smem + (bb2 ? FKTOFF : 0);
        ush* V = smem + FVBASE + (bb2 ? FVOFF : 0);
        int swm = (m & 7) << 3;
        float xb[32];
#pragma unroll
        for (int ssi = 0; ssi < 8; ++ssi) {
            int b0 = (grp * 4 + 64 * ssi) * NN;
            xb[ssi * 4 + 0] = src[b0]; xb[ssi * 4 + 1] = src[b0 + NN];
            xb[ssi * 4 + 2] = src[b0 + 2 * NN]; xb[ssi * 4 + 3] = src[b0 + 3 * NN];
        }
#pragma unroll
        for (int ssi = 0; ssi < 8; ++ssi) {
            int cb = grp * 4 + 64 * ssi;
            uint2 y = { pkbf(xb[ssi * 4 + 0] * sk, xb[ssi * 4 + 1] * sk),
                        pkbf(xb[ssi * 4 + 2] * sk, xb[ssi * 4 + 3] * sk) };
            *(uint2*)&KT[m * 512 + (cb ^ swm)] = y;
            ush* vb = &V[cb * FVSTR + m];
            vb[0] = sbf(xb[ssi * 4 + 0]); vb[FVSTR] = sbf(xb[ssi * 4 + 1]);
            vb[2 * FVSTR] = sbf(xb[ssi * 4 + 2]); vb[3 * FVSTR] = sbf(xb[ssi * 4 + 3]);
        }
    };
    f32x4 acc[8][2];
#pragma unroll
    for (int ci = 0; ci < 8; ++ci) { acc[ci][0] = (f32x4){0,0,0,0}; acc[ci][1] = (f32x4){0,0,0,0}; }
    float den_part = 0.f;
    stage(0, 0);
    const int mt = w >> 2, nt = w & 3, np = w & 1, cg = w >> 1;
    const int g = l >> 4, li = l & 15;
    const int mA = 16 * mt + li, swA = (mA & 7) << 3, nP = 16 * nt + li;
    for (int it = 0; it < 98; ++it) {
        int bb2 = it & 1;
        __syncthreads();
        f32x4 sacc = (f32x4){0,0,0,0};
        const ush* KT = smem + (bb2 ? FKTOFF : 0);
#pragma unroll
        for (int ks = 0; ks < 16; ++ks) {
            short8 af = *(const short8*)&KT[mA * 512 + ((ks * 32 + (g << 3)) ^ swA)];
            sacc = __builtin_amdgcn_mfma_f32_16x16x32_bf16(af, qf[ks], sacc, 0, 0, 0);
        }
        float p0 = __expf(sacc[0]), p1 = __expf(sacc[1]);
        float p2 = __expf(sacc[2]), p3 = __expf(sacc[3]);
        den_part += (p0 + p1) + (p2 + p3);
        uint2 pw = { pkbf(p0, p1), pkbf(p2, p3) };
        *(uint2*)&pp[nP * FVSTR + 16 * mt + 4 * g] = pw;
        if (it != 97) stage(it + 1, bb2 ^ 1);
        __syncthreads();
        const ush* V = smem + FVBASE + (bb2 ? FVOFF : 0);
        short8 bf0 = *(const short8*)&pp[(32 * np + li) * FVSTR + (g << 3)];
        short8 bf1 = *(const short8*)&pp[(32 * np + 16 + li) * FVSTR + (g << 3)];
        const ush* vbase = &V[(128 * cg + li) * FVSTR + (g << 3)];
#pragma unroll
        for (int ci = 0; ci < 8; ++ci) {
            short8 af = *(const short8*)&vbase[ci * 16 * FVSTR];
            acc[ci][0] = __builtin_amdgcn_mfma_f32_16x16x32_bf16(af, bf0, acc[ci][0], 0, 0, 0);
            acc[ci][1] = __builtin_amdgcn_mfma_f32_16x16x32_bf16(af, bf1, acc[ci][1], 0, 0, 0);
        }
    }
    den_part += __shfl_xor(den_part, 16);
    den_part += __shfl_xor(den_part, 32);
    if (l < 16) denbuf[w][l] = den_part;
    __syncthreads();
    float sc0 = 0.001f / (denbuf[2 * np + 0][li] + denbuf[4 + 2 * np + 0][li]);
    float sc1 = 0.001f / (denbuf[2 * np + 1][li] + denbuf[4 + 2 * np + 1][li]);
    float* op = out + (size_t)batch * CC * NN + n0;
    const int nc0 = 16 * (2 * np + 0) + li, nc1 = 16 * (2 * np + 1) + li;
#pragma unroll
    for (int ci = 0; ci < 8; ++ci) {
        int cbase = 16 * (8 * cg + ci) + 4 * g;
#pragma unroll
        for (int r = 0; r < 4; ++r) {
            atomicAdd(&op[(size_t)(cbase + r) * NN + nc0], acc[ci][0][r] * sc0);
            atomicAdd(&op[(size_t)(cbase + r) * NN + nc1], acc[ci][1][r] * sc1);
        }
    }
}

extern "C" void kernel_launch(void* const* d_in, const int* in_sizes, int n_in,
                              void* d_out, int out_size, void* d_ws, size_t ws_size,
                              hipStream_t stream) {
    (void)in_sizes; (void)n_in; (void)out_size;
    const float* f1 = (const float*)d_in[0];
    const float* f2 = (const float*)d_in[1];
    const float* f3 = (const float*)d_in[2];
    float* out = (float*)d_out;
    char* ws = (char*)d_ws;
    float* inv = (float*)(ws + INV_OFS);

    if (ws_size >= P_OFS + PER_TILE) {
        size_t tmax = (ws_size - P_OFS) / PER_TILE;
        int T = tmax < 25 ? (int)tmax : 25;
        int rowcap = T * 128;
        size_t PBRel = (size_t)T * 8 * 128 * NN;       // elems per branch
        float* den = (float*)(ws + DEN_OFS);
        ush* prep = (ush*)(ws + PREP_OFS);
        ush* qhatT = prep;
        ush* khatT = prep + TEN_ELE;                   // k2 then k3
        ush* vbf = prep + 3 * TEN_ELE;                 // v2 then v3
        ush* P = (ush*)(ws + P_OFS);
        norms_k<<<294, 256, 0, stream>>>(f1, f2, f3, inv);
        prepT_k<<<dim3(49, 8, 24), 256, 0, stream>>>(f1, f2, f3, inv, prep);
        prepC_k<<<dim3(6272, 2), 256, 0, stream>>>(f2, f3, vbf);
        hipMemsetAsync(den, 0, 200704, stream);
        for (int cbt = 0; cbt < 25; ) {
            int t = (25 - cbt) < T ? (25 - cbt) : T;
            gemmA_k<<<dim3(25 * t, 8, 2), 256, 0, stream>>>(qhatT, khatT, P, PBRel, den, cbt, rowcap);
            gemmB_k<<<dim3(4 * t, 8), 256, 0, stream>>>(vbf, P, PBRel, den, f1, out, cbt, rowcap);
            cbt += t;
        }
    } else {
        norms_k<<<294, 256, 0, stream>>>(f1, f2, f3, inv);
        init_k<<<12544, 256, 0, stream>>>((const float4*)f1, (float4*)out);
        attn_fb_k<<<784, 512, 0, stream>>>(f1, f2, f3, inv, out);
    }
}